// Round 3
// baseline (547.134 us; speedup 1.0000x reference)
//
#include <hip/hip_runtime.h>

#define HW     16384
#define BB     8
#define KK     19
#define CC     512
#define NS     32            // s-splits per (b, ctile)
#define SCHUNK (HW / NS)     // 512 spatial positions per block
#define SC4    (SCHUNK / 4)  // 128 float4 per k-row chunk
#define NW4    (KK * SC4)    // 2432 float4 staged per block (38 KB)

// ---------------- Stage 1: row softmax over spatial dim ----------------
// grid = B*K = 152 blocks, 512 threads. Row (16384 floats) in registers
// (8 float4/thread). Two block reductions (max, sum).
__global__ __launch_bounds__(512) void softmax_rows(const float* __restrict__ probs,
                                                    float* __restrict__ w) {
    const int row = blockIdx.x;                      // b*K + k
    const float4* p = reinterpret_cast<const float4*>(probs + (size_t)row * HW);
    float4* wr = reinterpret_cast<float4*>(w + (size_t)row * HW);
    const int tid = threadIdx.x;

    __shared__ float sred[8];

    float4 v[8];
    float m = -INFINITY;
    #pragma unroll
    for (int i = 0; i < 8; ++i) {
        v[i] = p[tid + i * 512];
        m = fmaxf(m, fmaxf(fmaxf(v[i].x, v[i].y), fmaxf(v[i].z, v[i].w)));
    }
    #pragma unroll
    for (int off = 32; off; off >>= 1) m = fmaxf(m, __shfl_xor(m, off));
    if ((tid & 63) == 0) sred[tid >> 6] = m;
    __syncthreads();
    #pragma unroll
    for (int i = 0; i < 8; ++i) m = fmaxf(m, sred[i]);
    __syncthreads();

    const float l2e = 1.44269504088896340736f;
    float s = 0.f;
    #pragma unroll
    for (int i = 0; i < 8; ++i) {
        v[i].x = exp2f((v[i].x - m) * l2e);
        v[i].y = exp2f((v[i].y - m) * l2e);
        v[i].z = exp2f((v[i].z - m) * l2e);
        v[i].w = exp2f((v[i].w - m) * l2e);
        s += (v[i].x + v[i].y) + (v[i].z + v[i].w);
    }
    #pragma unroll
    for (int off = 32; off; off >>= 1) s += __shfl_xor(s, off);
    if ((tid & 63) == 0) sred[tid >> 6] = s;
    __syncthreads();
    s = 0.f;
    #pragma unroll
    for (int i = 0; i < 8; ++i) s += sred[i];
    const float inv = 1.0f / s;

    #pragma unroll
    for (int i = 0; i < 8; ++i) {
        float4 o;
        o.x = v[i].x * inv; o.y = v[i].y * inv;
        o.z = v[i].z * inv; o.w = v[i].w * inv;
        wr[tid + i * 512] = o;
    }
}

// ---------------- Stage 2: ctx[b,c,k] = sum_s w[b,k,s] * f[b,c,s] ------
// Block = 256 threads, handles (b, 32 channels, SCHUNK spatial).
// Phase A: stage w[19][SCHUNK] into LDS (38 KB), coalesced.
// Phase B: s_idx = tid&15 strides s as float4, cg = tid>>4 owns 2 channels.
//   acc[19][2] = 38 VGPRs (fits: ~64 total, no spill). feats global->reg
//   (single pass over HBM), w via ds_read_b128 broadcast.
// Shuffle-reduce over 16 s-lanes, atomicAdd into zeroed output.
__global__ __launch_bounds__(256) void gather_ctx(const float* __restrict__ feats,
                                                  const float* __restrict__ w,
                                                  float* __restrict__ out) {
    __shared__ float4 wlds[NW4];                 // 38912 B

    const int bid   = blockIdx.x;
    const int ctile = bid & 15;                  // 16 ctiles x 32 channels
    const int ns    = (bid >> 4) & (NS - 1);
    const int b     = bid >> 9;
    const int tid   = threadIdx.x;

    // ---- Phase A: stage w chunk ----
    const float4* wg = reinterpret_cast<const float4*>(w + ((size_t)b * KK) * HW);
    #pragma unroll
    for (int i = 0; i < 10; ++i) {
        const int idx = tid + i * 256;
        if (idx < NW4) {
            const int k   = idx >> 7;            // /SC4
            const int s4l = idx & (SC4 - 1);
            wlds[idx] = wg[(size_t)k * (HW / 4) + ns * SC4 + s4l];
        }
    }
    __syncthreads();

    // ---- Phase B: accumulate ----
    const int s_idx = tid & 15;
    const int cg    = tid >> 4;
    const int c0    = ctile * 32 + cg * 2;
    const float4* f0 = reinterpret_cast<const float4*>(feats + ((size_t)(b * CC + c0)) * HW);
    const int s4g0 = ns * SC4;

    float acc[KK][2];
    #pragma unroll
    for (int k = 0; k < KK; ++k) { acc[k][0] = 0.f; acc[k][1] = 0.f; }

    #pragma unroll 1
    for (int it = 0; it < SC4 / 16; ++it) {      // 8 iterations
        const int s4l = it * 16 + s_idx;
        const float4 fa = f0[(size_t)(s4g0 + s4l)];
        const float4 fb = f0[(size_t)(HW / 4) + (s4g0 + s4l)];
        #pragma unroll
        for (int k = 0; k < KK; ++k) {
            const float4 ww = wlds[k * SC4 + s4l];
            acc[k][0] += ww.x * fa.x + ww.y * fa.y + ww.z * fa.z + ww.w * fa.w;
            acc[k][1] += ww.x * fb.x + ww.y * fb.y + ww.z * fb.z + ww.w * fb.w;
        }
    }

    // reduce across the 16 s-lanes (masks stay inside 16-lane group)
    #pragma unroll
    for (int k = 0; k < KK; ++k)
        #pragma unroll
        for (int j = 0; j < 2; ++j) {
            float v = acc[k][j];
            v += __shfl_xor(v, 1);
            v += __shfl_xor(v, 2);
            v += __shfl_xor(v, 4);
            v += __shfl_xor(v, 8);
            acc[k][j] = v;
        }

    if (s_idx == 0) {
        #pragma unroll
        for (int j = 0; j < 2; ++j)
            #pragma unroll
            for (int k = 0; k < KK; ++k)
                atomicAdd(&out[((size_t)(b * CC + c0 + j)) * KK + k], acc[k][j]);
    }
}

extern "C" void kernel_launch(void* const* d_in, const int* in_sizes, int n_in,
                              void* d_out, int out_size, void* d_ws, size_t ws_size,
                              hipStream_t stream) {
    const float* feats = (const float*)d_in[0];   // (8, 512, 128, 128)
    const float* probs = (const float*)d_in[1];   // (8, 19, 128, 128)
    float* out = (float*)d_out;                   // (8, 512, 19, 1)
    float* w   = (float*)d_ws;                    // B*K*HW floats = ~10 MB

    hipMemsetAsync(d_out, 0, (size_t)out_size * sizeof(float), stream);

    softmax_rows<<<BB * KK, 512, 0, stream>>>(probs, w);

    gather_ctx<<<BB * (CC / 32) * NS, 256, 0, stream>>>(feats, w, out);
}